// Round 1
// 495.377 us; speedup vs baseline: 1.0771x; 1.0771x over previous
//
#include <hip/hip_runtime.h>

// Problem constants (fixed by reference):
#define NB    32
#define CCH   256
#define HW    1024
#define NPIX  (NB*HW)     // 32768 pixels per input
#define DDICT 1024

#define EMB_ELEMS  ((size_t)NB*CCH*HW)      // 8388608
#define SEC_ELEMS  (2*EMB_ELEMS + NPIX)     // 16809984
#define PLANE_ELEMS ((size_t)NB*HW*CCH)     // 8388608 ushorts per bf16 plane

// MFMA GEMM tiling
#define TPX  128           // pixels per block
#define TD   128           // dicts per block
#define NDT  (DDICT/TD)    // 8 d-tiles
#define BK   32            // K per chunk (one 16x16x32 MFMA)
#define NKC  (CCH/BK)      // 8 chunks

#define TAU  0.125f        // near-tie threshold; 3-product split error <= ~6e-3 << TAU/2

typedef __attribute__((ext_vector_type(8))) short bf16x8;   // 8 bf16 = 4 VGPR
typedef __attribute__((ext_vector_type(4))) float f32x4;

// RNE round to bf16; returns bf16 bits, rest = exact residual.
__device__ inline ushort split_rne(float f, float& rest) {
    uint u = __float_as_uint(f);
    uint r = u + 0x7FFFu + ((u >> 16) & 1u);
    rest = f - __uint_as_float(r & 0xFFFF0000u);
    return (ushort)(r >> 16);
}

__device__ inline ushort rne_bf16(float f) {
    uint u = __float_as_uint(f);
    return (ushort)((u + 0x7FFFu + ((u >> 16) & 1u)) >> 16);
}

// ---------------- Stage 0a: dictionary norms (+ zero rescue counters) --------
// UNCHANGED arithmetic — rescue depends on bit-identical norms.
__global__ void dict_norms_kernel(const float* __restrict__ dict,
                                  float* __restrict__ norms,
                                  int* __restrict__ cnts) {
    if (blockIdx.x == 0 && threadIdx.x < 2) cnts[threadIdx.x] = 0;
    int d = blockIdx.x * blockDim.x + threadIdx.x;
    if (d < DDICT) {
        const float4* row = (const float4*)(dict + (size_t)d * CCH);
        float s = 0.f;
#pragma unroll 8
        for (int i = 0; i < CCH / 4; ++i) {
            float4 v = row[i];
            s += v.x * v.x + v.y * v.y + v.z * v.z + v.w * v.w;
        }
        norms[d] = s;
    }
}

// ---------------- Stage 0b: 2-way bf16 split of dictionary + fp32 transpose --
// dictT[k][d] = dict[d][k] (exact copy) -> coalesced rescue reads.
__global__ void dict_split_kernel(const float* __restrict__ dict,
                                  ushort* __restrict__ dH,
                                  ushort* __restrict__ dM,
                                  float* __restrict__ dictT) {
    int d = blockIdx.x;
    int lane = threadIdx.x;   // 0..63
    float4 f = ((const float4*)(dict + (size_t)d * CCH))[lane];
    float v[4] = {f.x, f.y, f.z, f.w};
    ushort h[4], m[4];
#pragma unroll
    for (int i = 0; i < 4; ++i) {
        float r1;
        h[i] = split_rne(v[i], r1);
        m[i] = rne_bf16(r1);
    }
    size_t o = (size_t)d * CCH + lane * 4;
    *(ushort4*)(dH + o) = make_ushort4(h[0], h[1], h[2], h[3]);
    *(ushort4*)(dM + o) = make_ushort4(m[0], m[1], m[2], m[3]);
#pragma unroll
    for (int j = 0; j < 4; ++j)
        dictT[(size_t)(lane * 4 + j) * DDICT + d] = v[j];
}

// ---------------- Stage 0c: pre-split + transpose of x ----------------------
// x [n][c][hw] fp32 -> xH/xM [n][pix][c] bf16 planes (scratch in d_out 2nd half).
// Transpose happens in registers: lane = pixel, 8 coalesced c-loads per octet.
__global__ __launch_bounds__(256)
void x_split_kernel(const float* __restrict__ x0, const float* __restrict__ x1,
                    ushort* __restrict__ xplanes) {
    const float* x = blockIdx.z ? x1 : x0;
    ushort* xH = xplanes + (size_t)blockIdx.z * 2 * PLANE_ELEMS;
    ushort* xM = xH + PLANE_ELEMS;
    const int lane = threadIdx.x & 63;
    const int wv   = threadIdx.x >> 6;
    const int n    = blockIdx.y;
    const int p    = blockIdx.x * 64 + lane;           // pixel (hw index)
    const float* xb = x + (size_t)n * CCH * HW + p;
    ushort* hb = xH + ((size_t)n * HW + p) * CCH;
    ushort* mb = xM + ((size_t)n * HW + p) * CCH;
    for (int i = 0; i < 8; ++i) {
        int c0 = (wv + i * 4) * 8;                     // this wave's c-octet
        uint hw_[4], mw_[4];
#pragma unroll
        for (int jj = 0; jj < 4; ++jj) {
            float f0 = xb[(size_t)(c0 + 2 * jj)     * HW];
            float f1 = xb[(size_t)(c0 + 2 * jj + 1) * HW];
            float r0, r1;
            ushort h0 = split_rne(f0, r0);
            ushort h1 = split_rne(f1, r1);
            hw_[jj] = (uint)h0 | ((uint)h1 << 16);
            mw_[jj] = (uint)rne_bf16(r0) | ((uint)rne_bf16(r1) << 16);
        }
        *(uint4*)(hb + c0) = make_uint4(hw_[0], hw_[1], hw_[2], hw_[3]);
        *(uint4*)(mb + c0) = make_uint4(mw_[0], mw_[1], mw_[2], mw_[3]);
    }
}

// ---------------- Stage 1: 3-product split-bf16 MFMA GEMM + partial top-2 ----
// grid (NDT, NPIX/TPX, 2 inputs), block 256 = 4 waves; wave wv owns pixels
// [wv*32,+32) x ALL 128 dicts. A-fragments are direct 16B loads from the
// pre-split planes (no in-kernel split, no scalar gathers).
__global__ __launch_bounds__(256, 2)
void vq_mfma_kernel(const ushort* __restrict__ xplanes,
                    const ushort* __restrict__ dH,
                    const ushort* __restrict__ dM,
                    const float* __restrict__ norms,
                    float* __restrict__ pdist,       // [2][NPIX][NDT] best
                    int*   __restrict__ pidx,        // [2][NPIX][NDT] best idx
                    float* __restrict__ psec) {      // [2][NPIX][NDT] second
    __shared__ ushort Bs[2][TD * BK];   // [plane][dd*32 + slot*8]  2 x 8 KB

    const int t    = threadIdx.x;
    const int lane = t & 63;
    const int wv   = t >> 6;
    const int lx   = lane & 15;      // MFMA row/col index
    const int q    = lane >> 4;      // k-octet
    const int m0w  = wv * 32;        // wave pixel offset
    const int z    = blockIdx.z;

    const int d0  = blockIdx.x * TD;
    const int g0  = blockIdx.y * TPX;
    const int n   = g0 / HW;
    const int hw0 = g0 % HW;         // tile stays within one n (128 | 1024)

    const ushort* xH = xplanes + (size_t)z * 2 * PLANE_ELEMS;
    const ushort* xM = xH + PLANE_ELEMS;
    const size_t prow = ((size_t)n * HW + hw0 + m0w + lx) * CCH;
    const ushort* aH = xH + prow + q * 8;
    const ushort* aM = xM + prow + q * 8;

    pdist += (size_t)z * NPIX * NDT;
    pidx  += (size_t)z * NPIX * NDT;
    psec  += (size_t)z * NPIX * NDT;

    f32x4 acc[2][8] = {};            // [mi][ni], 64 VGPR

    for (int kc = 0; kc < NKC; ++kc) {
        const int c0 = kc * BK;

        // ---- A fragments: direct 16B loads (wave covers 16 full 64B lines)
        bf16x8 Ah[2], Am[2];
#pragma unroll
        for (int mi = 0; mi < 2; ++mi) {
            Ah[mi] = *(const bf16x8*)(aH + (size_t)mi * 16 * CCH + c0);
            Am[mi] = *(const bf16x8*)(aM + (size_t)mi * 16 * CCH + c0);
        }

        __syncthreads();   // previous chunk's Bs frag reads complete

        // ---- B staging: 2 bf16 planes -> LDS, swizzled
#pragma unroll
        for (int plane = 0; plane < 2; ++plane) {
            const ushort* dp = plane ? dM : dH;
#pragma unroll
            for (int half = 0; half < 2; ++half) {
                int id  = half * 256 + t;
                int dd  = id >> 2, oct = id & 3;
                uint4 v = *(const uint4*)(dp + (size_t)(d0 + dd) * CCH + c0 + oct * 8);
                int slot = (oct + (dd >> 1)) & 3;
                *(uint4*)&Bs[plane][dd * 32 + slot * 8] = v;
            }
        }

        __syncthreads();

        // ---- MFMA: 3 split products (hh, hm, mh), fp32 accumulate
#pragma unroll
        for (int ni = 0; ni < 8; ++ni) {
            int nn   = ni * 16 + lx;
            int slot = (q + (nn >> 1)) & 3;
            int off  = nn * 32 + slot * 8;
            bf16x8 Bh = *(const bf16x8*)&Bs[0][off];
            bf16x8 Bm = *(const bf16x8*)&Bs[1][off];
#pragma unroll
            for (int mi = 0; mi < 2; ++mi) {
                f32x4 c = acc[mi][ni];
                c = __builtin_amdgcn_mfma_f32_16x16x32_bf16(Ah[mi], Bh, c, 0, 0, 0);
                c = __builtin_amdgcn_mfma_f32_16x16x32_bf16(Ah[mi], Bm, c, 0, 0, 0);
                c = __builtin_amdgcn_mfma_f32_16x16x32_bf16(Am[mi], Bh, c, 0, 0, 0);
                acc[mi][ni] = c;
            }
        }
    }

    // ---- Epilogue: dist = norm - 2*dot; per-pixel top-2 (b1, i1, b2).
    float nrm[8];
#pragma unroll
    for (int ni = 0; ni < 8; ++ni) nrm[ni] = norms[d0 + ni * 16 + lx];

#pragma unroll
    for (int mi = 0; mi < 2; ++mi)
#pragma unroll
        for (int r = 0; r < 4; ++r) {
            float b1 = 3.0e38f, b2 = 3.0e38f; int i1 = 0;
#pragma unroll
            for (int ni = 0; ni < 8; ++ni) {        // ascending dict within lane
                float dist = fmaf(-2.f, acc[mi][ni][r], nrm[ni]);
                if (dist < b1)      { b2 = b1; b1 = dist; i1 = ni * 16 + lx; }
                else if (dist < b2) { b2 = dist; }
            }
#pragma unroll
            for (int off = 1; off < 16; off <<= 1) { // 16-lane group, idx tie-break
                float o1 = __shfl_xor(b1, off);
                int   oi = __shfl_xor(i1, off);
                float o2 = __shfl_xor(b2, off);
                if (o1 < b1 || (o1 == b1 && oi < i1)) {
                    b2 = fminf(b1, o2); b1 = o1; i1 = oi;
                } else {
                    b2 = fminf(b2, o1);
                }
            }
            if (lx == 0) {
                int g = g0 + m0w + mi * 16 + q * 4 + r;   // C-row = quad*4 + reg
                pdist[(size_t)g * NDT + blockIdx.x] = b1;
                pidx [(size_t)g * NDT + blockIdx.x] = d0 + i1;
                psec [(size_t)g * NDT + blockIdx.x] = b2;
            }
        }
}

// ---------------- Stage 2: final top-2 merge + flag + gather + writes --------
__global__ void vq_finalize_kernel(const float* __restrict__ pdist,
                                   const int*   __restrict__ pidx,
                                   const float* __restrict__ psec,
                                   const float* __restrict__ dict,
                                   float* __restrict__ out,
                                   int* __restrict__ cnts,
                                   int* __restrict__ lists) {
    __shared__ int idx_s[64];
    const int z  = blockIdx.z;
    pdist += (size_t)z * NPIX * NDT;
    pidx  += (size_t)z * NPIX * NDT;
    psec  += (size_t)z * NPIX * NDT;
    float* out_emb    = out + (size_t)z * SEC_ELEMS;
    float* out_emb_pt = out_emb + EMB_ELEMS;
    float* out_idx    = out_emb + 2 * EMB_ELEMS;
    int* cnt  = cnts + z;
    int* list = lists + (size_t)z * NPIX;

    const int t  = threadIdx.x;
    const int g0 = blockIdx.x * 64;

    if (t < 64) {
        int g = g0 + t;
        float pd_[8]; int pi_[8]; float ps_[8];
        *(float4*)&pd_[0] = *(const float4*)(pdist + (size_t)g * NDT);
        *(float4*)&pd_[4] = *(const float4*)(pdist + (size_t)g * NDT + 4);
        *(int4*)  &pi_[0] = *(const int4*)  (pidx  + (size_t)g * NDT);
        *(int4*)  &pi_[4] = *(const int4*)  (pidx  + (size_t)g * NDT + 4);
        *(float4*)&ps_[0] = *(const float4*)(psec  + (size_t)g * NDT);
        *(float4*)&ps_[4] = *(const float4*)(psec  + (size_t)g * NDT + 4);
        float b1 = pd_[0]; int i1 = pi_[0]; float b2 = ps_[0];
#pragma unroll
        for (int qk = 1; qk < 8; ++qk) {   // ascending tile: lowest idx on ties
            float c1 = pd_[qk], c2 = ps_[qk]; int ci = pi_[qk];
            if (c1 < b1) { b2 = fminf(b1, c2); b1 = c1; i1 = ci; }
            else         { b2 = fminf(b2, c1); }
        }
        idx_s[t] = i1;
        out_idx[g] = (float)i1;
        if (b2 - b1 < TAU) {               // near-tie: exact-fp32 rescue later
            int slot = atomicAdd(cnt, 1);
            list[slot] = g;
        }
    }
    __syncthreads();

    const int p4 = t & 15;    // 4-pixel group
    const int cg = t >> 4;    // 16 channel-groups of 16 channels
    const int nb = g0 / HW;
    const int hw = (g0 % HW) + p4 * 4;
    const float* r0 = dict + (size_t)idx_s[p4 * 4 + 0] * CCH;
    const float* r1 = dict + (size_t)idx_s[p4 * 4 + 1] * CCH;
    const float* r2 = dict + (size_t)idx_s[p4 * 4 + 2] * CCH;
    const float* r3 = dict + (size_t)idx_s[p4 * 4 + 3] * CCH;
    const size_t obase = (size_t)nb * CCH * HW + hw;

#pragma unroll
    for (int cq = 0; cq < 4; ++cq) {
        int c = cg * 16 + cq * 4;
        float4 q0 = *(const float4*)(r0 + c);
        float4 q1 = *(const float4*)(r1 + c);
        float4 q2 = *(const float4*)(r2 + c);
        float4 q3 = *(const float4*)(r3 + c);
        float4 v0 = make_float4(q0.x, q1.x, q2.x, q3.x);
        float4 v1 = make_float4(q0.y, q1.y, q2.y, q3.y);
        float4 v2 = make_float4(q0.z, q1.z, q2.z, q3.z);
        float4 v3 = make_float4(q0.w, q1.w, q2.w, q3.w);
        *(float4*)(out_emb    + obase + (size_t)(c + 0) * HW) = v0;
        *(float4*)(out_emb_pt + obase + (size_t)(c + 0) * HW) = v0;
        *(float4*)(out_emb    + obase + (size_t)(c + 1) * HW) = v1;
        *(float4*)(out_emb_pt + obase + (size_t)(c + 1) * HW) = v1;
        *(float4*)(out_emb    + obase + (size_t)(c + 2) * HW) = v2;
        *(float4*)(out_emb_pt + obase + (size_t)(c + 2) * HW) = v2;
        *(float4*)(out_emb    + obase + (size_t)(c + 3) * HW) = v3;
        *(float4*)(out_emb_pt + obase + (size_t)(c + 3) * HW) = v3;
    }
}

// ---------------- Stage 3: exact-fp32 rescue of near-tie pixels --------------
// Bit-identical arithmetic to prior rounds: fmaf chain, k ascending;
// dist = fmaf(-2,dot,norm); lexicographic (dist,idx) argmin. The only change
// is the dict read path: dictT[k][d] (exact fp32 copy) -> coalesced lanes.
__global__ __launch_bounds__(256)
void vq_rescue_kernel(const float* __restrict__ x0,
                      const float* __restrict__ x1,
                      const float* __restrict__ dictT,
                      const float* __restrict__ dict,
                      const float* __restrict__ norms,
                      const int* __restrict__ cnts,
                      const int* __restrict__ lists,
                      float* __restrict__ out) {
    __shared__ float xr[CCH];
    __shared__ float rd_s[4];
    __shared__ int   ri_s[4];
    __shared__ int   bi_s;
    const int z = blockIdx.z;
    const float* x = z ? x1 : x0;
    const int* list = lists + (size_t)z * NPIX;
    float* out_emb    = out + (size_t)z * SEC_ELEMS;
    float* out_emb_pt = out_emb + EMB_ELEMS;
    float* out_idx    = out_emb + 2 * EMB_ELEMS;
    const int t    = threadIdx.x;
    const int lane = t & 63;
    const int wv   = t >> 6;
    const int total = cnts[z];

    for (int w = blockIdx.x; w < total; w += gridDim.x) {
        const int g  = list[w];
        const int n  = g / HW;
        const int hw = g % HW;
        xr[t] = x[(size_t)n * CCH * HW + (size_t)t * HW + hw];
        __syncthreads();

        float bd = 3.0e38f; int bi = 0;
#pragma unroll
        for (int dd = 0; dd < 4; ++dd) {          // dicts {t, 256+t, 512+t, 768+t}
            int d = dd * 256 + t;                 // ascending within thread
            float dot = 0.f;
#pragma unroll 8
            for (int k = 0; k < CCH; ++k)
                dot = fmaf(xr[k], dictT[(size_t)k * DDICT + d], dot);
            float dist = fmaf(-2.f, dot, norms[d]);
            if (dist < bd) { bd = dist; bi = d; }
        }
#pragma unroll
        for (int off = 1; off < 64; off <<= 1) {  // wave lexicographic min
            float od = __shfl_xor(bd, off);
            int   oi = __shfl_xor(bi, off);
            if (od < bd || (od == bd && oi < bi)) { bd = od; bi = oi; }
        }
        if (lane == 0) { rd_s[wv] = bd; ri_s[wv] = bi; }
        __syncthreads();
        if (t == 0) {
            float fb = rd_s[0]; int fi = ri_s[0];
#pragma unroll
            for (int q2 = 1; q2 < 4; ++q2)
                if (rd_s[q2] < fb || (rd_s[q2] == fb && ri_s[q2] < fi)) {
                    fb = rd_s[q2]; fi = ri_s[q2];
                }
            bi_s = fi;
            out_idx[g] = (float)fi;
        }
        __syncthreads();
        float v = dict[(size_t)bi_s * CCH + t];
        size_t o = (size_t)n * CCH * HW + (size_t)t * HW + hw;
        out_emb[o]    = v;
        out_emb_pt[o] = v;
        __syncthreads();   // xr reused next iteration
    }
}

extern "C" void kernel_launch(void* const* d_in, const int* in_sizes, int n_in,
                              void* d_out, int out_size, void* d_ws, size_t ws_size,
                              hipStream_t stream) {
    const float* x0   = (const float*)d_in[0];
    const float* x1   = (const float*)d_in[1];
    const float* dict = (const float*)d_in[2];
    float* out = (float*)d_out;

    // ws layout (bytes): norms 4K | dH/dM 2x512K | dictT 1M |
    //                    pdist 2x1M | pidx 2x1M | psec 2x1M | lists 2x128K | cnts 8
    float*  norms = (float*)d_ws;
    ushort* dH    = (ushort*)(norms + DDICT);
    ushort* dM    = dH + (size_t)DDICT * CCH;
    float*  dictT = (float*)(dM + (size_t)DDICT * CCH);
    float*  pdist = dictT + (size_t)DDICT * CCH;           // [2][NPIX][NDT]
    int*    pidx  = (int*)(pdist + 2 * (size_t)NPIX * NDT);
    float*  psec  = (float*)(pidx + 2 * (size_t)NPIX * NDT);
    int*    lists = (int*)(psec + 2 * (size_t)NPIX * NDT); // [2][NPIX]
    int*    cnts  = lists + 2 * NPIX;

    // A-plane scratch lives in the 2nd half of d_out (67.2 MB >= 64 MB needed).
    // Safe: finalize/rescue z=1 write that region only AFTER vq_mfma consumed it.
    ushort* xplanes = (ushort*)(out + SEC_ELEMS);

    dict_norms_kernel<<<dim3(DDICT / 256), dim3(256), 0, stream>>>(dict, norms, cnts);
    dict_split_kernel<<<dim3(DDICT), dim3(64), 0, stream>>>(dict, dH, dM, dictT);
    x_split_kernel<<<dim3(HW / 64, NB, 2), dim3(256), 0, stream>>>(x0, x1, xplanes);

    vq_mfma_kernel<<<dim3(NDT, NPIX / TPX, 2), dim3(256), 0, stream>>>(
        xplanes, dH, dM, norms, pdist, pidx, psec);

    vq_finalize_kernel<<<dim3(NPIX / 64, 1, 2), dim3(256), 0, stream>>>(
        pdist, pidx, psec, dict, out, cnts, lists);

    vq_rescue_kernel<<<dim3(1024, 1, 2), dim3(256), 0, stream>>>(
        x0, x1, dictT, dict, norms, cnts, lists, out);
}

// Round 2
// 471.356 us; speedup vs baseline: 1.1320x; 1.0510x over previous
//
#include <hip/hip_runtime.h>

// Problem constants (fixed by reference):
#define NB    32
#define CCH   256
#define HW    1024
#define NPIX  (NB*HW)     // 32768 pixels per input
#define DDICT 1024

#define EMB_ELEMS  ((size_t)NB*CCH*HW)      // 8388608
#define SEC_ELEMS  (2*EMB_ELEMS + NPIX)     // 16809984
#define PLANE_ELEMS ((size_t)NB*HW*CCH)     // 8388608 ushorts per bf16 plane

// MFMA GEMM tiling
#define TPX  128           // pixels per block
#define TD   128           // dicts per tile
#define NDT  (DDICT/TD)    // 8 d-tiles (all processed by each block now)
#define BK   32            // K per chunk (one 16x16x32 MFMA)
#define NKC  (CCH/BK)      // 8 chunks
#define NPH  (NDT*NKC)     // 64 staging phases

#define TAU  0.125f        // near-tie threshold; 3-product split error <= ~6e-3 << TAU/2

typedef __attribute__((ext_vector_type(8))) short bf16x8;   // 8 bf16 = 4 VGPR
typedef __attribute__((ext_vector_type(4))) float f32x4;

// RNE round to bf16; returns bf16 bits, rest = exact residual.
__device__ inline ushort split_rne(float f, float& rest) {
    uint u = __float_as_uint(f);
    uint r = u + 0x7FFFu + ((u >> 16) & 1u);
    rest = f - __uint_as_float(r & 0xFFFF0000u);
    return (ushort)(r >> 16);
}

__device__ inline ushort rne_bf16(float f) {
    uint u = __float_as_uint(f);
    return (ushort)((u + 0x7FFFu + ((u >> 16) & 1u)) >> 16);
}

// async 16B global->LDS (linear dest: wave-uniform base + lane*16)
__device__ inline void gll16(const void* g, void* l) {
    __builtin_amdgcn_global_load_lds(
        (const __attribute__((address_space(1))) uint*)g,
        (__attribute__((address_space(3))) uint*)l,
        16, 0, 0);
}

// ---------------- Stage 0a: dictionary norms (+ zero rescue counters) --------
// UNCHANGED arithmetic — rescue depends on bit-identical norms.
__global__ void dict_norms_kernel(const float* __restrict__ dict,
                                  float* __restrict__ norms,
                                  int* __restrict__ cnts) {
    if (blockIdx.x == 0 && threadIdx.x < 2) cnts[threadIdx.x] = 0;
    int d = blockIdx.x * blockDim.x + threadIdx.x;
    if (d < DDICT) {
        const float4* row = (const float4*)(dict + (size_t)d * CCH);
        float s = 0.f;
#pragma unroll 8
        for (int i = 0; i < CCH / 4; ++i) {
            float4 v = row[i];
            s += v.x * v.x + v.y * v.y + v.z * v.z + v.w * v.w;
        }
        norms[d] = s;
    }
}

// ---------------- Stage 0b: 2-way bf16 split of dictionary, PRE-TILED --------
// dHs/dMs layout: per (dt,kc) an 8KB chunk laid out exactly as the LDS image:
// elem = dd*32 + slot*8 + e, slot=(oct+(dd>>1))&3 — so vq_mfma stages with
// linear global_load_lds and the frag reads keep the bank-conflict-free swizzle.
// dictT[k][d] = dict[d][k] (exact fp32 copy) -> coalesced rescue reads.
__global__ void dict_split_kernel(const float* __restrict__ dict,
                                  ushort* __restrict__ dHs,
                                  ushort* __restrict__ dMs,
                                  float* __restrict__ dictT) {
    int d = blockIdx.x;
    int lane = threadIdx.x;   // 0..63
    float4 f = ((const float4*)(dict + (size_t)d * CCH))[lane];
    float v[4] = {f.x, f.y, f.z, f.w};
    ushort h[4], m[4];
#pragma unroll
    for (int i = 0; i < 4; ++i) {
        float r1;
        h[i] = split_rne(v[i], r1);
        m[i] = rne_bf16(r1);
    }
    int c0 = lane * 4;                        // 4 consecutive channels, same octet
    int kc = c0 >> 5, oct = (c0 >> 3) & 3, e0 = c0 & 7;
    int dt = d >> 7, dd = d & 127;
    int slot = (oct + (dd >> 1)) & 3;
    size_t base = ((size_t)(dt * NKC + kc)) * 4096 + dd * 32 + slot * 8 + e0;
    *(ushort4*)(dHs + base) = make_ushort4(h[0], h[1], h[2], h[3]);
    *(ushort4*)(dMs + base) = make_ushort4(m[0], m[1], m[2], m[3]);
#pragma unroll
    for (int j = 0; j < 4; ++j)
        dictT[(size_t)(c0 + j) * DDICT + d] = v[j];
}

// ---------------- Stage 0c: pre-split + transpose of x ----------------------
// x [n][c][hw] fp32 -> xH/xM [n][pix][c] bf16 planes (scratch in d_out 2nd half).
__global__ __launch_bounds__(256)
void x_split_kernel(const float* __restrict__ x0, const float* __restrict__ x1,
                    ushort* __restrict__ xplanes) {
    const float* x = blockIdx.z ? x1 : x0;
    ushort* xH = xplanes + (size_t)blockIdx.z * 2 * PLANE_ELEMS;
    ushort* xM = xH + PLANE_ELEMS;
    const int lane = threadIdx.x & 63;
    const int wv   = threadIdx.x >> 6;
    const int n    = blockIdx.y;
    const int p    = blockIdx.x * 64 + lane;           // pixel (hw index)
    const float* xb = x + (size_t)n * CCH * HW + p;
    ushort* hb = xH + ((size_t)n * HW + p) * CCH;
    ushort* mb = xM + ((size_t)n * HW + p) * CCH;
    for (int i = 0; i < 8; ++i) {
        int c0 = (wv + i * 4) * 8;                     // this wave's c-octet
        uint hw_[4], mw_[4];
#pragma unroll
        for (int jj = 0; jj < 4; ++jj) {
            float f0 = xb[(size_t)(c0 + 2 * jj)     * HW];
            float f1 = xb[(size_t)(c0 + 2 * jj + 1) * HW];
            float r0, r1;
            ushort h0 = split_rne(f0, r0);
            ushort h1 = split_rne(f1, r1);
            hw_[jj] = (uint)h0 | ((uint)h1 << 16);
            mw_[jj] = (uint)rne_bf16(r0) | ((uint)rne_bf16(r1) << 16);
        }
        *(uint4*)(hb + c0) = make_uint4(hw_[0], hw_[1], hw_[2], hw_[3]);
        *(uint4*)(mb + c0) = make_uint4(mw_[0], mw_[1], mw_[2], mw_[3]);
    }
}

// ---------------- Stage 1: all-dict MFMA + fused top-2 merge -----------------
// grid (NPIX/TPX, 2 inputs), block 256 = 4 waves; wave wv owns pixels
// [wv*32,+32). A (both planes, all 8 K-chunks) lives in registers (128 VGPR),
// read ONCE from HBM. d-tiles loop inside: B staged via global_load_lds from
// the pre-tiled image into double-buffered LDS, 1 barrier/phase. Per-tile
// (b1,i1,b2) arithmetic is bit-identical to round 1; the cross-tile merge
// replicates finalize's ascending strict-< semantics, so final idx + flag set
// are unchanged. Writes out_idx directly + near-tie list (no partial buffers).
__global__ __launch_bounds__(256, 2)
void vq_mfma_kernel(const ushort* __restrict__ xplanes,
                    const ushort* __restrict__ dHs,
                    const ushort* __restrict__ dMs,
                    const float* __restrict__ norms,
                    float* __restrict__ out,
                    int* __restrict__ cnts,
                    int* __restrict__ lists) {
    __shared__ ushort Bs[2][2][4096];   // [buf][plane][8KB]  32 KB total

    const int t    = threadIdx.x;
    const int lane = t & 63;
    const int wv   = t >> 6;
    const int lx   = lane & 15;      // MFMA row/col index
    const int q    = lane >> 4;      // k-octet
    const int m0w  = wv * 32;        // wave pixel offset
    const int z    = blockIdx.y;

    const int g0  = blockIdx.x * TPX;
    const int n   = g0 / HW;
    const int hw0 = g0 % HW;         // tile stays within one n (128 | 1024)

    const ushort* xH = xplanes + (size_t)z * 2 * PLANE_ELEMS;
    const ushort* xM = xH + PLANE_ELEMS;
    const size_t prow = ((size_t)n * HW + hw0 + m0w + lx) * CCH;
    const ushort* aH = xH + prow + q * 8;
    const ushort* aM = xM + prow + q * 8;

    float* out_idx = out + (size_t)z * SEC_ELEMS + 2 * EMB_ELEMS;
    int* cnt  = cnts + z;
    int* list = lists + (size_t)z * NPIX;

    // ---- A: both planes, all K, in registers (read once)
    bf16x8 Ah[8][2], Am[8][2];
#pragma unroll
    for (int kc = 0; kc < 8; ++kc)
#pragma unroll
        for (int mi = 0; mi < 2; ++mi) {
            Ah[kc][mi] = *(const bf16x8*)(aH + (size_t)mi * 16 * CCH + kc * BK);
            Am[kc][mi] = *(const bf16x8*)(aM + (size_t)mi * 16 * CCH + kc * BK);
        }

    // stage phase p (8KB x 2 planes) into buf b: 4 x global_load_lds_dwordx4
    auto stage = [&](int p, int b) {
#pragma unroll
        for (int plane = 0; plane < 2; ++plane) {
            const ushort* sp = (plane ? dMs : dHs) + (size_t)p * 4096;
#pragma unroll
            for (int half = 0; half < 2; ++half) {
                gll16(sp + (half * 256 + t) * 8,
                      &Bs[b][plane][half * 2048 + wv * 512]);
            }
        }
    };
    stage(0, 0);

    // running top-2 per owned pixel-row
    float b1r[2][4], b2r[2][4]; int i1r[2][4];
#pragma unroll
    for (int mi = 0; mi < 2; ++mi)
#pragma unroll
        for (int r = 0; r < 4; ++r) {
            b1r[mi][r] = 3.0e38f; b2r[mi][r] = 3.0e38f; i1r[mi][r] = 0;
        }

    int cur = 0;
    for (int dt = 0; dt < NDT; ++dt) {
        f32x4 acc[2][8] = {};            // reset per tile (same as round 1)
#pragma unroll
        for (int kc = 0; kc < 8; ++kc) {
            __syncthreads();             // buf[cur] staged (vmcnt drained here)
            int p = dt * 8 + kc;
            if (p + 1 < NPH) stage(p + 1, cur ^ 1);   // flies under MFMA below
            const ushort* bb = &Bs[cur][0][0];
#pragma unroll
            for (int ni = 0; ni < 8; ++ni) {
                int nn   = ni * 16 + lx;
                int slot = (q + (nn >> 1)) & 3;
                int off  = nn * 32 + slot * 8;
                bf16x8 Bh = *(const bf16x8*)(bb + off);
                bf16x8 Bm = *(const bf16x8*)(bb + 4096 + off);
#pragma unroll
                for (int mi = 0; mi < 2; ++mi) {
                    f32x4 c = acc[mi][ni];
                    c = __builtin_amdgcn_mfma_f32_16x16x32_bf16(Ah[kc][mi], Bh, c, 0, 0, 0);
                    c = __builtin_amdgcn_mfma_f32_16x16x32_bf16(Ah[kc][mi], Bm, c, 0, 0, 0);
                    c = __builtin_amdgcn_mfma_f32_16x16x32_bf16(Am[kc][mi], Bh, c, 0, 0, 0);
                    acc[mi][ni] = c;
                }
            }
            cur ^= 1;
        }

        // ---- per-tile epilogue: top-2 within tile (bit-identical to round 1),
        //      then ascending strict-< merge (== finalize's qk loop).
        const int d0 = dt * TD;
        float nrm[8];
#pragma unroll
        for (int ni = 0; ni < 8; ++ni) nrm[ni] = norms[d0 + ni * 16 + lx];

#pragma unroll
        for (int mi = 0; mi < 2; ++mi)
#pragma unroll
            for (int r = 0; r < 4; ++r) {
                float c1 = 3.0e38f, c2 = 3.0e38f; int ci = 0;
#pragma unroll
                for (int ni = 0; ni < 8; ++ni) {    // ascending dict within lane
                    float dist = fmaf(-2.f, acc[mi][ni][r], nrm[ni]);
                    if (dist < c1)      { c2 = c1; c1 = dist; ci = ni * 16 + lx; }
                    else if (dist < c2) { c2 = dist; }
                }
#pragma unroll
                for (int off = 1; off < 16; off <<= 1) { // 16-lane, idx tie-break
                    float o1 = __shfl_xor(c1, off);
                    int   oi = __shfl_xor(ci, off);
                    float o2 = __shfl_xor(c2, off);
                    if (o1 < c1 || (o1 == c1 && oi < ci)) {
                        c2 = fminf(c1, o2); c1 = o1; ci = oi;
                    } else {
                        c2 = fminf(c2, o1);
                    }
                }
                if (c1 < b1r[mi][r]) {
                    b2r[mi][r] = fminf(b1r[mi][r], c2);
                    b1r[mi][r] = c1;
                    i1r[mi][r] = d0 + ci;
                } else {
                    b2r[mi][r] = fminf(b2r[mi][r], c1);
                }
            }
    }

    // ---- final write: idx for every pixel + near-tie rescue list
#pragma unroll
    for (int mi = 0; mi < 2; ++mi)
#pragma unroll
        for (int r = 0; r < 4; ++r) {
            if (lx == 0) {
                int g = g0 + m0w + mi * 16 + q * 4 + r;   // C-row = quad*4 + reg
                out_idx[g] = (float)i1r[mi][r];
                if (b2r[mi][r] - b1r[mi][r] < TAU) {
                    int slot = atomicAdd(cnt, 1);
                    list[slot] = g;
                }
            }
        }
}

// ---------------- Stage 2: gather + embedded writes --------------------------
__global__ void vq_gather_kernel(const float* __restrict__ dict,
                                 float* __restrict__ out) {
    __shared__ int idx_s[64];
    const int z = blockIdx.z;
    float* out_emb    = out + (size_t)z * SEC_ELEMS;
    float* out_emb_pt = out_emb + EMB_ELEMS;
    const float* out_idx = out_emb + 2 * EMB_ELEMS;

    const int t  = threadIdx.x;
    const int g0 = blockIdx.x * 64;

    if (t < 64) idx_s[t] = (int)out_idx[g0 + t];
    __syncthreads();

    const int p4 = t & 15;    // 4-pixel group
    const int cg = t >> 4;    // 16 channel-groups of 16 channels
    const int nb = g0 / HW;
    const int hw = (g0 % HW) + p4 * 4;
    const float* r0 = dict + (size_t)idx_s[p4 * 4 + 0] * CCH;
    const float* r1 = dict + (size_t)idx_s[p4 * 4 + 1] * CCH;
    const float* r2 = dict + (size_t)idx_s[p4 * 4 + 2] * CCH;
    const float* r3 = dict + (size_t)idx_s[p4 * 4 + 3] * CCH;
    const size_t obase = (size_t)nb * CCH * HW + hw;

#pragma unroll
    for (int cq = 0; cq < 4; ++cq) {
        int c = cg * 16 + cq * 4;
        float4 q0 = *(const float4*)(r0 + c);
        float4 q1 = *(const float4*)(r1 + c);
        float4 q2 = *(const float4*)(r2 + c);
        float4 q3 = *(const float4*)(r3 + c);
        float4 v0 = make_float4(q0.x, q1.x, q2.x, q3.x);
        float4 v1 = make_float4(q0.y, q1.y, q2.y, q3.y);
        float4 v2 = make_float4(q0.z, q1.z, q2.z, q3.z);
        float4 v3 = make_float4(q0.w, q1.w, q2.w, q3.w);
        *(float4*)(out_emb    + obase + (size_t)(c + 0) * HW) = v0;
        *(float4*)(out_emb_pt + obase + (size_t)(c + 0) * HW) = v0;
        *(float4*)(out_emb    + obase + (size_t)(c + 1) * HW) = v1;
        *(float4*)(out_emb_pt + obase + (size_t)(c + 1) * HW) = v1;
        *(float4*)(out_emb    + obase + (size_t)(c + 2) * HW) = v2;
        *(float4*)(out_emb_pt + obase + (size_t)(c + 2) * HW) = v2;
        *(float4*)(out_emb    + obase + (size_t)(c + 3) * HW) = v3;
        *(float4*)(out_emb_pt + obase + (size_t)(c + 3) * HW) = v3;
    }
}

// ---------------- Stage 3: exact-fp32 rescue of near-tie pixels --------------
// UNCHANGED from round 1 (bit-identical arithmetic; coalesced dictT reads).
__global__ __launch_bounds__(256)
void vq_rescue_kernel(const float* __restrict__ x0,
                      const float* __restrict__ x1,
                      const float* __restrict__ dictT,
                      const float* __restrict__ dict,
                      const float* __restrict__ norms,
                      const int* __restrict__ cnts,
                      const int* __restrict__ lists,
                      float* __restrict__ out) {
    __shared__ float xr[CCH];
    __shared__ float rd_s[4];
    __shared__ int   ri_s[4];
    __shared__ int   bi_s;
    const int z = blockIdx.z;
    const float* x = z ? x1 : x0;
    const int* list = lists + (size_t)z * NPIX;
    float* out_emb    = out + (size_t)z * SEC_ELEMS;
    float* out_emb_pt = out_emb + EMB_ELEMS;
    float* out_idx    = out_emb + 2 * EMB_ELEMS;
    const int t    = threadIdx.x;
    const int lane = t & 63;
    const int wv   = t >> 6;
    const int total = cnts[z];

    for (int w = blockIdx.x; w < total; w += gridDim.x) {
        const int g  = list[w];
        const int n  = g / HW;
        const int hw = g % HW;
        xr[t] = x[(size_t)n * CCH * HW + (size_t)t * HW + hw];
        __syncthreads();

        float bd = 3.0e38f; int bi = 0;
#pragma unroll
        for (int dd = 0; dd < 4; ++dd) {          // dicts {t, 256+t, 512+t, 768+t}
            int d = dd * 256 + t;                 // ascending within thread
            float dot = 0.f;
#pragma unroll 8
            for (int k = 0; k < CCH; ++k)
                dot = fmaf(xr[k], dictT[(size_t)k * DDICT + d], dot);
            float dist = fmaf(-2.f, dot, norms[d]);
            if (dist < bd) { bd = dist; bi = d; }
        }
#pragma unroll
        for (int off = 1; off < 64; off <<= 1) {  // wave lexicographic min
            float od = __shfl_xor(bd, off);
            int   oi = __shfl_xor(bi, off);
            if (od < bd || (od == bd && oi < bi)) { bd = od; bi = oi; }
        }
        if (lane == 0) { rd_s[wv] = bd; ri_s[wv] = bi; }
        __syncthreads();
        if (t == 0) {
            float fb = rd_s[0]; int fi = ri_s[0];
#pragma unroll
            for (int q2 = 1; q2 < 4; ++q2)
                if (rd_s[q2] < fb || (rd_s[q2] == fb && ri_s[q2] < fi)) {
                    fb = rd_s[q2]; fi = ri_s[q2];
                }
            bi_s = fi;
            out_idx[g] = (float)fi;
        }
        __syncthreads();
        float v = dict[(size_t)bi_s * CCH + t];
        size_t o = (size_t)n * CCH * HW + (size_t)t * HW + hw;
        out_emb[o]    = v;
        out_emb_pt[o] = v;
        __syncthreads();   // xr reused next iteration
    }
}

extern "C" void kernel_launch(void* const* d_in, const int* in_sizes, int n_in,
                              void* d_out, int out_size, void* d_ws, size_t ws_size,
                              hipStream_t stream) {
    const float* x0   = (const float*)d_in[0];
    const float* x1   = (const float*)d_in[1];
    const float* dict = (const float*)d_in[2];
    float* out = (float*)d_out;

    // ws layout: norms 4K | dHs 512K | dMs 512K | dictT 1M | lists 2x128K | cnts 8
    float*  norms = (float*)d_ws;
    ushort* dHs   = (ushort*)(norms + DDICT);
    ushort* dMs   = dHs + (size_t)DDICT * CCH;
    float*  dictT = (float*)(dMs + (size_t)DDICT * CCH);
    int*    lists = (int*)(dictT + (size_t)DDICT * CCH);   // [2][NPIX]
    int*    cnts  = lists + 2 * NPIX;

    // A-plane scratch in the 2nd half of d_out: floats [SEC_ELEMS, SEC+16777216).
    // z=0 idx region ends at SEC_ELEMS (abuts, no overlap); z=1 idx region
    // starts at SEC+2*EMB = SEC+16777216 (abuts end, no overlap). z=1 emb
    // writes (which DO overlap xplanes) happen only in gather/rescue, after
    // vq_mfma has consumed xplanes.
    ushort* xplanes = (ushort*)(out + SEC_ELEMS);

    dict_norms_kernel<<<dim3(DDICT / 256), dim3(256), 0, stream>>>(dict, norms, cnts);
    dict_split_kernel<<<dim3(DDICT), dim3(64), 0, stream>>>(dict, dHs, dMs, dictT);
    x_split_kernel<<<dim3(HW / 64, NB, 2), dim3(256), 0, stream>>>(x0, x1, xplanes);

    vq_mfma_kernel<<<dim3(NPIX / TPX, 2), dim3(256), 0, stream>>>(
        xplanes, dHs, dMs, norms, out, cnts, lists);

    vq_gather_kernel<<<dim3(NPIX / 64, 1, 2), dim3(256), 0, stream>>>(dict, out);

    vq_rescue_kernel<<<dim3(1024, 1, 2), dim3(256), 0, stream>>>(
        x0, x1, dictT, dict, norms, cnts, lists, out);
}

// Round 3
// 402.766 us; speedup vs baseline: 1.3248x; 1.1703x over previous
//
#include <hip/hip_runtime.h>

// Problem constants (fixed by reference):
#define NB    32
#define CCH   256
#define HW    1024
#define NPIX  (NB*HW)     // 32768 pixels per input
#define DDICT 1024

#define EMB_ELEMS  ((size_t)NB*CCH*HW)      // 8388608
#define SEC_ELEMS  (2*EMB_ELEMS + NPIX)     // 16809984

// MFMA GEMM tiling
#define TPX  128           // pixels per block
#define TD   128           // dicts per tile
#define NDT  (DDICT/TD)    // 8 d-tiles (all processed by each block)
#define BK   32            // K per chunk (one 16x16x32 MFMA)
#define NKC  (CCH/BK)      // 8 chunks
#define NPH  (NDT*NKC)     // 64 staging phases

#define TAU  0.125f        // near-tie threshold; split error ~6e-3 << TAU/2

typedef __attribute__((ext_vector_type(8))) short bf16x8;   // 8 bf16 = 4 VGPR
typedef __attribute__((ext_vector_type(4))) float f32x4;

// RNE round to bf16; returns bf16 bits, rest = exact residual.
__device__ inline ushort split_rne(float f, float& rest) {
    uint u = __float_as_uint(f);
    uint r = u + 0x7FFFu + ((u >> 16) & 1u);
    rest = f - __uint_as_float(r & 0xFFFF0000u);
    return (ushort)(r >> 16);
}

__device__ inline ushort rne_bf16(float f) {
    uint u = __float_as_uint(f);
    return (ushort)((u + 0x7FFFu + ((u >> 16) & 1u)) >> 16);
}

// async 16B global->LDS (linear dest: wave-uniform base + lane*16)
__device__ inline void gll16(const void* g, void* l) {
    __builtin_amdgcn_global_load_lds(
        (const __attribute__((address_space(1))) uint*)g,
        (__attribute__((address_space(3))) uint*)l,
        16, 0, 0);
}

// ---------------- Stage 0a: dictionary norms (+ zero rescue counters) --------
// UNCHANGED arithmetic — rescue + epilogue depend on bit-identical norms.
__global__ void dict_norms_kernel(const float* __restrict__ dict,
                                  float* __restrict__ norms,
                                  int* __restrict__ cnts) {
    if (blockIdx.x == 0 && threadIdx.x < 2) cnts[threadIdx.x] = 0;
    int d = blockIdx.x * blockDim.x + threadIdx.x;
    if (d < DDICT) {
        const float4* row = (const float4*)(dict + (size_t)d * CCH);
        float s = 0.f;
#pragma unroll 8
        for (int i = 0; i < CCH / 4; ++i) {
            float4 v = row[i];
            s += v.x * v.x + v.y * v.y + v.z * v.z + v.w * v.w;
        }
        norms[d] = s;
    }
}

// ---------------- Stage 0b: 2-way bf16 split of dictionary, PRE-TILED --------
// dHs/dMs: per (dt,kc) an 8KB chunk that IS the LDS image (swizzle baked in):
// elem = dd*32 + slot*8 + e, slot=(oct+(dd>>1))&3. vq_mfma stages it with
// linear global_load_lds. dictT[k][d] = exact fp32 transpose for rescue.
__global__ void dict_split_kernel(const float* __restrict__ dict,
                                  ushort* __restrict__ dHs,
                                  ushort* __restrict__ dMs,
                                  float* __restrict__ dictT) {
    int d = blockIdx.x;
    int lane = threadIdx.x;   // 0..63
    float4 f = ((const float4*)(dict + (size_t)d * CCH))[lane];
    float v[4] = {f.x, f.y, f.z, f.w};
    ushort h[4], m[4];
#pragma unroll
    for (int i = 0; i < 4; ++i) {
        float r1;
        h[i] = split_rne(v[i], r1);
        m[i] = rne_bf16(r1);
    }
    int c0 = lane * 4;                        // 4 consecutive channels, one octet
    int kc = c0 >> 5, oct = (c0 >> 3) & 3, e0 = c0 & 7;
    int dt = d >> 7, dd = d & 127;
    int slot = (oct + (dd >> 1)) & 3;
    size_t base = ((size_t)(dt * NKC + kc)) * 4096 + dd * 32 + slot * 8 + e0;
    *(ushort4*)(dHs + base) = make_ushort4(h[0], h[1], h[2], h[3]);
    *(ushort4*)(dMs + base) = make_ushort4(m[0], m[1], m[2], m[3]);
#pragma unroll
    for (int j = 0; j < 4; ++j)
        dictT[(size_t)(c0 + j) * DDICT + d] = v[j];
}

// ---------------- Stage 1: fused all-dict MFMA + top-2 + idx + emb writes ----
// grid (NPIX/TPX, 2 inputs), block 256 = 4 waves; wave wv owns pixels
// [wv*32,+32). A: x read DIRECTLY (coalesced fp32), 2-way split ONCE in regs
// (amortized over all 1024 dicts). B: triple-buffered LDS via global_load_lds
// with COUNTED vmcnt — stage loads stay in flight across raw s_barrier (T4):
//   per phase p: s_waitcnt vmcnt(4) [retire stage(p), keep stage(p+1)]
//                s_barrier ; issue stage(p+2) ; setprio(1) MFMA setprio(0)
// WAR-safe: stage(p+2) targets buf (p-1)%3 post-barrier; phase p-1 readers
// provably retired (their ds_reads were consumed by issued MFMAs) before any
// wave exits that barrier. Loop has ZERO compiler VMEM (norms live in LDS) so
// the vmcnt counts are exact. Epilogue: per-tile top-2 + cross-tile merge
// (bit-identical to round 2), then fused dict-gather writes emb/emb_pt.
__global__ __launch_bounds__(256, 2)
void vq_mfma_kernel(const float* __restrict__ x0,
                    const float* __restrict__ x1,
                    const ushort* __restrict__ dHs,
                    const ushort* __restrict__ dMs,
                    const float* __restrict__ norms,
                    const float* __restrict__ dict,
                    float* __restrict__ out,
                    int* __restrict__ cnts,
                    int* __restrict__ lists) {
    __shared__ ushort Bs[3][2][4096];   // [buf][plane][8KB]  48 KB
    __shared__ float nrm_s[DDICT];      // 4 KB (exact copy of norms)
    __shared__ int   idx_s[TPX];        // 512 B

    const int t    = threadIdx.x;
    const int lane = t & 63;
    const int wv   = t >> 6;
    const int lx   = lane & 15;      // MFMA row/col index
    const int q    = lane >> 4;      // k-octet
    const int m0w  = wv * 32;        // wave pixel offset
    const int z    = blockIdx.y;

    const int g0  = blockIdx.x * TPX;
    const int n   = g0 / HW;
    const int hw0 = g0 % HW;         // tile stays within one n (128 | 1024)

    const float* x = z ? x1 : x0;
    float* out_base = out + (size_t)z * SEC_ELEMS;
    float* out_idx  = out_base + 2 * EMB_ELEMS;
    int* cnt  = cnts + z;
    int* list = lists + (size_t)z * NPIX;

    // norms -> LDS (bitwise copy; keeps the K-loop free of compiler VMEM)
    *(float4*)(nrm_s + t * 4) = *(const float4*)(norms + t * 4);

    // ---- A: direct coalesced fp32 reads of x + exact 2-way split, ONCE
    const float* xbase = x + (size_t)n * CCH * HW + hw0 + m0w + lx;
    bf16x8 Ah[8][2], Am[8][2];
#pragma unroll
    for (int kc = 0; kc < NKC; ++kc) {
        float a_f[2][8];
#pragma unroll
        for (int mi = 0; mi < 2; ++mi)
#pragma unroll
            for (int j = 0; j < 8; ++j)
                a_f[mi][j] = xbase[(size_t)(kc * BK + q * 8 + j) * HW + mi * 16];
#pragma unroll
        for (int mi = 0; mi < 2; ++mi)
#pragma unroll
            for (int j = 0; j < 8; ++j) {
                float r1;
                ushort h = split_rne(a_f[mi][j], r1);
                Ah[kc][mi][j] = (short)h;
                Am[kc][mi][j] = (short)rne_bf16(r1);
            }
    }

    // stage phase p (8KB x 2 planes) into buf b: 4 gll16 per thread
    auto stage = [&](int p, int b) {
#pragma unroll
        for (int plane = 0; plane < 2; ++plane) {
            const ushort* sp = (plane ? dMs : dHs) + (size_t)p * 4096;
#pragma unroll
            for (int half = 0; half < 2; ++half) {
                gll16(sp + (half * 256 + t) * 8,
                      &Bs[b][plane][half * 2048 + wv * 512]);
            }
        }
    };

    __syncthreads();          // nrm_s visible; x-loads fully drained (vmcnt 0)
    stage(0, 0);
    stage(1, 1);

    // running top-2 per owned pixel-row
    float b1r[2][4], b2r[2][4]; int i1r[2][4];
#pragma unroll
    for (int mi = 0; mi < 2; ++mi)
#pragma unroll
        for (int r = 0; r < 4; ++r) {
            b1r[mi][r] = 3.0e38f; b2r[mi][r] = 3.0e38f; i1r[mi][r] = 0;
        }

    int rb = 0;   // read buffer  = p % 3
    int sb = 2;   // stage target = (p+2) % 3
    for (int dt = 0; dt < NDT; ++dt) {
        f32x4 acc[2][8] = {};            // reset per tile (same as round 2)
#pragma unroll
        for (int kc = 0; kc < NKC; ++kc) {
            if (dt == NDT - 1 && kc == NKC - 1)
                asm volatile("s_waitcnt vmcnt(0)" ::: "memory");  // last phase
            else
                asm volatile("s_waitcnt vmcnt(4)" ::: "memory");  // keep p+1 in flight
            __builtin_amdgcn_s_barrier();
            if (!(dt == NDT - 1 && kc >= NKC - 2))
                stage(dt * 8 + kc + 2, sb);

            const ushort* bb = &Bs[rb][0][0];
            __builtin_amdgcn_s_setprio(1);
#pragma unroll
            for (int ni = 0; ni < 8; ++ni) {
                int nn   = ni * 16 + lx;
                int slot = (q + (nn >> 1)) & 3;
                int off  = nn * 32 + slot * 8;
                bf16x8 Bh = *(const bf16x8*)(bb + off);
                bf16x8 Bm = *(const bf16x8*)(bb + 4096 + off);
#pragma unroll
                for (int mi = 0; mi < 2; ++mi) {
                    f32x4 c = acc[mi][ni];
                    c = __builtin_amdgcn_mfma_f32_16x16x32_bf16(Ah[kc][mi], Bh, c, 0, 0, 0);
                    c = __builtin_amdgcn_mfma_f32_16x16x32_bf16(Ah[kc][mi], Bm, c, 0, 0, 0);
                    c = __builtin_amdgcn_mfma_f32_16x16x32_bf16(Am[kc][mi], Bh, c, 0, 0, 0);
                    acc[mi][ni] = c;
                }
            }
            __builtin_amdgcn_s_setprio(0);
            rb = (rb == 2) ? 0 : rb + 1;
            sb = (sb == 2) ? 0 : sb + 1;
        }

        // ---- per-tile epilogue: top-2 within tile, then ascending strict-<
        //      merge — bit-identical to round 2 (nrm_s is a bitwise norms copy).
        const int d0 = dt * TD;
        float nrm[8];
#pragma unroll
        for (int ni = 0; ni < 8; ++ni) nrm[ni] = nrm_s[d0 + ni * 16 + lx];

#pragma unroll
        for (int mi = 0; mi < 2; ++mi)
#pragma unroll
            for (int r = 0; r < 4; ++r) {
                float c1 = 3.0e38f, c2 = 3.0e38f; int ci = 0;
#pragma unroll
                for (int ni = 0; ni < 8; ++ni) {    // ascending dict within lane
                    float dist = fmaf(-2.f, acc[mi][ni][r], nrm[ni]);
                    if (dist < c1)      { c2 = c1; c1 = dist; ci = ni * 16 + lx; }
                    else if (dist < c2) { c2 = dist; }
                }
#pragma unroll
                for (int off = 1; off < 16; off <<= 1) { // 16-lane, idx tie-break
                    float o1 = __shfl_xor(c1, off);
                    int   oi = __shfl_xor(ci, off);
                    float o2 = __shfl_xor(c2, off);
                    if (o1 < c1 || (o1 == c1 && oi < ci)) {
                        c2 = fminf(c1, o2); c1 = o1; ci = oi;
                    } else {
                        c2 = fminf(c2, o1);
                    }
                }
                if (c1 < b1r[mi][r]) {
                    b2r[mi][r] = fminf(b1r[mi][r], c2);
                    b1r[mi][r] = c1;
                    i1r[mi][r] = d0 + ci;
                } else {
                    b2r[mi][r] = fminf(b2r[mi][r], c1);
                }
            }
    }

    // ---- final: idx + rescue flags, then fused dict-gather emb writes
#pragma unroll
    for (int mi = 0; mi < 2; ++mi)
#pragma unroll
        for (int r = 0; r < 4; ++r) {
            if (lx == 0) {
                int loc = m0w + mi * 16 + q * 4 + r;      // C-row = quad*4 + reg
                int g = g0 + loc;
                idx_s[loc] = i1r[mi][r];
                out_idx[g] = (float)i1r[mi][r];
                if (b2r[mi][r] - b1r[mi][r] < TAU) {
                    int slot = atomicAdd(cnt, 1);
                    list[slot] = g;
                }
            }
        }
    __syncthreads();

    // gather-transpose-write for this block's 128 pixels (dict L2-resident)
    const int pg = t & 31;    // 32 groups of 4 pixels
    const int cg = t >> 5;    // 8 channel-groups of 32 channels
    const int hwp = hw0 + pg * 4;
    const float* r0 = dict + (size_t)idx_s[pg * 4 + 0] * CCH;
    const float* r1 = dict + (size_t)idx_s[pg * 4 + 1] * CCH;
    const float* r2 = dict + (size_t)idx_s[pg * 4 + 2] * CCH;
    const float* r3 = dict + (size_t)idx_s[pg * 4 + 3] * CCH;
    float* oe = out_base;
    float* op = out_base + EMB_ELEMS;
    const size_t obase = (size_t)n * CCH * HW + hwp;

#pragma unroll
    for (int cq = 0; cq < 8; ++cq) {
        int c = cg * 32 + cq * 4;
        float4 q0 = *(const float4*)(r0 + c);
        float4 q1 = *(const float4*)(r1 + c);
        float4 q2 = *(const float4*)(r2 + c);
        float4 q3 = *(const float4*)(r3 + c);
        float4 v0 = make_float4(q0.x, q1.x, q2.x, q3.x);
        float4 v1 = make_float4(q0.y, q1.y, q2.y, q3.y);
        float4 v2 = make_float4(q0.z, q1.z, q2.z, q3.z);
        float4 v3 = make_float4(q0.w, q1.w, q2.w, q3.w);
        *(float4*)(oe + obase + (size_t)(c + 0) * HW) = v0;
        *(float4*)(op + obase + (size_t)(c + 0) * HW) = v0;
        *(float4*)(oe + obase + (size_t)(c + 1) * HW) = v1;
        *(float4*)(op + obase + (size_t)(c + 1) * HW) = v1;
        *(float4*)(oe + obase + (size_t)(c + 2) * HW) = v2;
        *(float4*)(op + obase + (size_t)(c + 2) * HW) = v2;
        *(float4*)(oe + obase + (size_t)(c + 3) * HW) = v3;
        *(float4*)(op + obase + (size_t)(c + 3) * HW) = v3;
    }
}

// ---------------- Stage 3: exact-fp32 rescue of near-tie pixels --------------
// UNCHANGED (bit-identical arithmetic; coalesced dictT reads).
__global__ __launch_bounds__(256)
void vq_rescue_kernel(const float* __restrict__ x0,
                      const float* __restrict__ x1,
                      const float* __restrict__ dictT,
                      const float* __restrict__ dict,
                      const float* __restrict__ norms,
                      const int* __restrict__ cnts,
                      const int* __restrict__ lists,
                      float* __restrict__ out) {
    __shared__ float xr[CCH];
    __shared__ float rd_s[4];
    __shared__ int   ri_s[4];
    __shared__ int   bi_s;
    const int z = blockIdx.z;
    const float* x = z ? x1 : x0;
    const int* list = lists + (size_t)z * NPIX;
    float* out_emb    = out + (size_t)z * SEC_ELEMS;
    float* out_emb_pt = out_emb + EMB_ELEMS;
    float* out_idx    = out_emb + 2 * EMB_ELEMS;
    const int t    = threadIdx.x;
    const int lane = t & 63;
    const int wv   = t >> 6;
    const int total = cnts[z];

    for (int w = blockIdx.x; w < total; w += gridDim.x) {
        const int g  = list[w];
        const int n  = g / HW;
        const int hw = g % HW;
        xr[t] = x[(size_t)n * CCH * HW + (size_t)t * HW + hw];
        __syncthreads();

        float bd = 3.0e38f; int bi = 0;
#pragma unroll
        for (int dd = 0; dd < 4; ++dd) {          // dicts {t, 256+t, 512+t, 768+t}
            int d = dd * 256 + t;                 // ascending within thread
            float dot = 0.f;
#pragma unroll 8
            for (int k = 0; k < CCH; ++k)
                dot = fmaf(xr[k], dictT[(size_t)k * DDICT + d], dot);
            float dist = fmaf(-2.f, dot, norms[d]);
            if (dist < bd) { bd = dist; bi = d; }
        }
#pragma unroll
        for (int off = 1; off < 64; off <<= 1) {  // wave lexicographic min
            float od = __shfl_xor(bd, off);
            int   oi = __shfl_xor(bi, off);
            if (od < bd || (od == bd && oi < bi)) { bd = od; bi = oi; }
        }
        if (lane == 0) { rd_s[wv] = bd; ri_s[wv] = bi; }
        __syncthreads();
        if (t == 0) {
            float fb = rd_s[0]; int fi = ri_s[0];
#pragma unroll
            for (int q2 = 1; q2 < 4; ++q2)
                if (rd_s[q2] < fb || (rd_s[q2] == fb && ri_s[q2] < fi)) {
                    fb = rd_s[q2]; fi = ri_s[q2];
                }
            bi_s = fi;
            out_idx[g] = (float)fi;
        }
        __syncthreads();
        float v = dict[(size_t)bi_s * CCH + t];
        size_t o = (size_t)n * CCH * HW + (size_t)t * HW + hw;
        out_emb[o]    = v;
        out_emb_pt[o] = v;
        __syncthreads();   // xr reused next iteration
    }
}

extern "C" void kernel_launch(void* const* d_in, const int* in_sizes, int n_in,
                              void* d_out, int out_size, void* d_ws, size_t ws_size,
                              hipStream_t stream) {
    const float* x0   = (const float*)d_in[0];
    const float* x1   = (const float*)d_in[1];
    const float* dict = (const float*)d_in[2];
    float* out = (float*)d_out;

    // ws layout: norms 4K | dHs 512K | dMs 512K | dictT 1M | lists 2x128K | cnts 8
    float*  norms = (float*)d_ws;
    ushort* dHs   = (ushort*)(norms + DDICT);
    ushort* dMs   = dHs + (size_t)DDICT * CCH;
    float*  dictT = (float*)(dMs + (size_t)DDICT * CCH);
    int*    lists = (int*)(dictT + (size_t)DDICT * CCH);   // [2][NPIX]
    int*    cnts  = lists + 2 * NPIX;

    dict_norms_kernel<<<dim3(DDICT / 256), dim3(256), 0, stream>>>(dict, norms, cnts);
    dict_split_kernel<<<dim3(DDICT), dim3(64), 0, stream>>>(dict, dHs, dMs, dictT);

    vq_mfma_kernel<<<dim3(NPIX / TPX, 2), dim3(256), 0, stream>>>(
        x0, x1, dHs, dMs, norms, dict, out, cnts, lists);

    vq_rescue_kernel<<<dim3(1024, 1, 2), dim3(256), 0, stream>>>(
        x0, x1, dictT, dict, norms, cnts, lists, out);
}

// Round 4
// 395.078 us; speedup vs baseline: 1.3505x; 1.0195x over previous
//
#include <hip/hip_runtime.h>

// Problem constants (fixed by reference):
#define NB    32
#define CCH   256
#define HW    1024
#define NPIX  (NB*HW)     // 32768 pixels per input
#define DDICT 1024

#define EMB_ELEMS  ((size_t)NB*CCH*HW)      // 8388608
#define SEC_ELEMS  (2*EMB_ELEMS + NPIX)     // 16809984

// MFMA GEMM tiling
#define TPX  128           // pixels per block
#define TD   128           // dicts per tile
#define NDT  (DDICT/TD)    // 8 d-tiles (all processed by each block)
#define BK   32            // K per chunk (one 16x16x32 MFMA)
#define NKC  (CCH/BK)      // 8 chunks
#define NPH2 (NDT*NKC/2)   // 32 merged staging phases (2 chunks each)

#define TAU  0.125f        // near-tie threshold; split error ~6e-3 << TAU/2

typedef __attribute__((ext_vector_type(8))) short bf16x8;   // 8 bf16 = 4 VGPR
typedef __attribute__((ext_vector_type(4))) float f32x4;

// RNE round to bf16; returns bf16 bits, rest = exact residual.
__device__ inline ushort split_rne(float f, float& rest) {
    uint u = __float_as_uint(f);
    uint r = u + 0x7FFFu + ((u >> 16) & 1u);
    rest = f - __uint_as_float(r & 0xFFFF0000u);
    return (ushort)(r >> 16);
}

__device__ inline ushort rne_bf16(float f) {
    uint u = __float_as_uint(f);
    return (ushort)((u + 0x7FFFu + ((u >> 16) & 1u)) >> 16);
}

// async 16B global->LDS (linear dest: wave-uniform base + lane*16)
__device__ inline void gll16(const void* g, void* l) {
    __builtin_amdgcn_global_load_lds(
        (const __attribute__((address_space(1))) uint*)g,
        (__attribute__((address_space(3))) uint*)l,
        16, 0, 0);
}

// ---------------- Stage 0a: dictionary norms (+ zero rescue counters) --------
// UNCHANGED arithmetic — rescue + epilogue depend on bit-identical norms.
__global__ void dict_norms_kernel(const float* __restrict__ dict,
                                  float* __restrict__ norms,
                                  int* __restrict__ cnts) {
    if (blockIdx.x == 0 && threadIdx.x < 2) cnts[threadIdx.x] = 0;
    int d = blockIdx.x * blockDim.x + threadIdx.x;
    if (d < DDICT) {
        const float4* row = (const float4*)(dict + (size_t)d * CCH);
        float s = 0.f;
#pragma unroll 8
        for (int i = 0; i < CCH / 4; ++i) {
            float4 v = row[i];
            s += v.x * v.x + v.y * v.y + v.z * v.z + v.w * v.w;
        }
        norms[d] = s;
    }
}

// ---------------- Stage 0b: 2-way bf16 split of dictionary, PRE-TILED --------
// dHs/dMs: per (dt,kc) an 8KB chunk that IS the LDS image (swizzle baked in):
// elem = dd*32 + slot*8 + e, slot=(oct+(dd>>1))&3. vq_mfma stages chunk PAIRS
// (16KB contiguous) with linear global_load_lds. dictT = fp32 transpose.
__global__ void dict_split_kernel(const float* __restrict__ dict,
                                  ushort* __restrict__ dHs,
                                  ushort* __restrict__ dMs,
                                  float* __restrict__ dictT) {
    int d = blockIdx.x;
    int lane = threadIdx.x;   // 0..63
    float4 f = ((const float4*)(dict + (size_t)d * CCH))[lane];
    float v[4] = {f.x, f.y, f.z, f.w};
    ushort h[4], m[4];
#pragma unroll
    for (int i = 0; i < 4; ++i) {
        float r1;
        h[i] = split_rne(v[i], r1);
        m[i] = rne_bf16(r1);
    }
    int c0 = lane * 4;                        // 4 consecutive channels, one octet
    int kc = c0 >> 5, oct = (c0 >> 3) & 3, e0 = c0 & 7;
    int dt = d >> 7, dd = d & 127;
    int slot = (oct + (dd >> 1)) & 3;
    size_t base = ((size_t)(dt * NKC + kc)) * 4096 + dd * 32 + slot * 8 + e0;
    *(ushort4*)(dHs + base) = make_ushort4(h[0], h[1], h[2], h[3]);
    *(ushort4*)(dMs + base) = make_ushort4(m[0], m[1], m[2], m[3]);
#pragma unroll
    for (int j = 0; j < 4; ++j)
        dictT[(size_t)(c0 + j) * DDICT + d] = v[j];
}

// ---------------- Stage 1: fused all-dict MFMA + top-2 + idx + emb writes ----
// grid (NPIX/TPX, 2 inputs) = 512 blocks -> exactly 2 blocks/CU (grid-capped
// occupancy), so per-barrier overhead must be amortized, not hidden: phases
// are MERGED to BK=64 (96 MFMA/wave per barrier, 32 phases). Double-buffered
// LDS (2x32KB) with a full-phase staging lead:
//   phase p: s_waitcnt vmcnt(0)  [stage(p), issued one full phase ago ~3000cyc]
//            s_barrier ; stage(p+1) -> buf (p+1)&1 ; setprio(1) 96 MFMA (0)
// WAR-safe: buf (p+1)&1 was read in phase p-1; every wave's p-1 ds_reads
// completed (lgkmcnt before its MFMAs) before it entered barrier(p).
// Accumulation order per acc element is bit-identical to round 3
// (kc = kh*2+kk ascending, same 3-product sequence) -> selection unchanged.
__global__ __launch_bounds__(256, 2)
void vq_mfma_kernel(const float* __restrict__ x0,
                    const float* __restrict__ x1,
                    const ushort* __restrict__ dHs,
                    const ushort* __restrict__ dMs,
                    const float* __restrict__ norms,
                    const float* __restrict__ dict,
                    float* __restrict__ out,
                    int* __restrict__ cnts,
                    int* __restrict__ lists) {
    __shared__ ushort Bs[2][2][8192];   // [buf][plane][2 kc-chunks] 64 KB
    __shared__ float nrm_s[DDICT];      // 4 KB (exact copy of norms)
    __shared__ int   idx_s[TPX];        // 512 B

    const int t    = threadIdx.x;
    const int lane = t & 63;
    const int wv   = t >> 6;
    const int lx   = lane & 15;      // MFMA row/col index
    const int q    = lane >> 4;      // k-octet
    const int m0w  = wv * 32;        // wave pixel offset
    const int z    = blockIdx.y;

    const int g0  = blockIdx.x * TPX;
    const int n   = g0 / HW;
    const int hw0 = g0 % HW;         // tile stays within one n (128 | 1024)

    const float* x = z ? x1 : x0;
    float* out_base = out + (size_t)z * SEC_ELEMS;
    float* out_idx  = out_base + 2 * EMB_ELEMS;
    int* cnt  = cnts + z;
    int* list = lists + (size_t)z * NPIX;

    // norms -> LDS (bitwise copy; keeps the K-loop free of compiler VMEM)
    *(float4*)(nrm_s + t * 4) = *(const float4*)(norms + t * 4);

    // ---- A: direct coalesced fp32 reads of x + exact 2-way split, ONCE
    const float* xbase = x + (size_t)n * CCH * HW + hw0 + m0w + lx;
    bf16x8 Ah[8][2], Am[8][2];
#pragma unroll
    for (int kc = 0; kc < NKC; ++kc) {
        float a_f[2][8];
#pragma unroll
        for (int mi = 0; mi < 2; ++mi)
#pragma unroll
            for (int j = 0; j < 8; ++j)
                a_f[mi][j] = xbase[(size_t)(kc * BK + q * 8 + j) * HW + mi * 16];
#pragma unroll
        for (int mi = 0; mi < 2; ++mi)
#pragma unroll
            for (int j = 0; j < 8; ++j) {
                float r1;
                ushort h = split_rne(a_f[mi][j], r1);
                Ah[kc][mi][j] = (short)h;
                Am[kc][mi][j] = (short)rne_bf16(r1);
            }
    }

    // stage merged phase p (2 chunks x 2 planes = 32 KB): 8 gll16 per thread
    auto stage = [&](int p, int b) {
#pragma unroll
        for (int plane = 0; plane < 2; ++plane) {
            const ushort* sp = (plane ? dMs : dHs) + (size_t)p * 8192;
#pragma unroll
            for (int h = 0; h < 4; ++h) {
                gll16(sp + (h * 256 + t) * 8,
                      &Bs[b][plane][h * 2048 + wv * 512]);
            }
        }
    };

    __syncthreads();          // nrm_s visible; x-loads drained by their uses
    stage(0, 0);

    // running top-2 per owned pixel-row
    float b1r[2][4], b2r[2][4]; int i1r[2][4];
#pragma unroll
    for (int mi = 0; mi < 2; ++mi)
#pragma unroll
        for (int r = 0; r < 4; ++r) {
            b1r[mi][r] = 3.0e38f; b2r[mi][r] = 3.0e38f; i1r[mi][r] = 0;
        }

    for (int dt = 0; dt < NDT; ++dt) {
        f32x4 acc[2][8] = {};            // reset per tile (same as round 3)
#pragma unroll
        for (int kh = 0; kh < 4; ++kh) {
            const int p = dt * 4 + kh;
            asm volatile("s_waitcnt vmcnt(0)" ::: "memory");  // stage(p) done
            __builtin_amdgcn_s_barrier();
            if (p + 1 < NPH2) stage(p + 1, (p + 1) & 1);      // full-phase lead

            const ushort* bb = &Bs[p & 1][0][0];
            __builtin_amdgcn_s_setprio(1);
#pragma unroll
            for (int ni = 0; ni < 8; ++ni) {
                int nn   = ni * 16 + lx;
                int slot = (q + (nn >> 1)) & 3;
                int off  = nn * 32 + slot * 8;
#pragma unroll
                for (int kk = 0; kk < 2; ++kk) {
                    const int kc = kh * 2 + kk;
                    bf16x8 Bh = *(const bf16x8*)(bb + kk * 4096 + off);
                    bf16x8 Bm = *(const bf16x8*)(bb + 8192 + kk * 4096 + off);
#pragma unroll
                    for (int mi = 0; mi < 2; ++mi) {
                        f32x4 c = acc[mi][ni];
                        c = __builtin_amdgcn_mfma_f32_16x16x32_bf16(Ah[kc][mi], Bh, c, 0, 0, 0);
                        c = __builtin_amdgcn_mfma_f32_16x16x32_bf16(Ah[kc][mi], Bm, c, 0, 0, 0);
                        c = __builtin_amdgcn_mfma_f32_16x16x32_bf16(Am[kc][mi], Bh, c, 0, 0, 0);
                        acc[mi][ni] = c;
                    }
                }
            }
            __builtin_amdgcn_s_setprio(0);
        }

        // ---- per-tile epilogue: top-2 within tile, then ascending strict-<
        //      merge — bit-identical to round 3 (nrm_s is a bitwise norms copy).
        const int d0 = dt * TD;
        float nrm[8];
#pragma unroll
        for (int ni = 0; ni < 8; ++ni) nrm[ni] = nrm_s[d0 + ni * 16 + lx];

#pragma unroll
        for (int mi = 0; mi < 2; ++mi)
#pragma unroll
            for (int r = 0; r < 4; ++r) {
                float c1 = 3.0e38f, c2 = 3.0e38f; int ci = 0;
#pragma unroll
                for (int ni = 0; ni < 8; ++ni) {    // ascending dict within lane
                    float dist = fmaf(-2.f, acc[mi][ni][r], nrm[ni]);
                    if (dist < c1)      { c2 = c1; c1 = dist; ci = ni * 16 + lx; }
                    else if (dist < c2) { c2 = dist; }
                }
#pragma unroll
                for (int off = 1; off < 16; off <<= 1) { // 16-lane, idx tie-break
                    float o1 = __shfl_xor(c1, off);
                    int   oi = __shfl_xor(ci, off);
                    float o2 = __shfl_xor(c2, off);
                    if (o1 < c1 || (o1 == c1 && oi < ci)) {
                        c2 = fminf(c1, o2); c1 = o1; ci = oi;
                    } else {
                        c2 = fminf(c2, o1);
                    }
                }
                if (c1 < b1r[mi][r]) {
                    b2r[mi][r] = fminf(b1r[mi][r], c2);
                    b1r[mi][r] = c1;
                    i1r[mi][r] = d0 + ci;
                } else {
                    b2r[mi][r] = fminf(b2r[mi][r], c1);
                }
            }
    }

    // ---- final: idx + rescue flags, then fused dict-gather emb writes
#pragma unroll
    for (int mi = 0; mi < 2; ++mi)
#pragma unroll
        for (int r = 0; r < 4; ++r) {
            if (lx == 0) {
                int loc = m0w + mi * 16 + q * 4 + r;      // C-row = quad*4 + reg
                int g = g0 + loc;
                idx_s[loc] = i1r[mi][r];
                out_idx[g] = (float)i1r[mi][r];
                if (b2r[mi][r] - b1r[mi][r] < TAU) {
                    int slot = atomicAdd(cnt, 1);
                    list[slot] = g;
                }
            }
        }
    __syncthreads();

    // gather-transpose-write for this block's 128 pixels (dict L2-resident)
    const int pg = t & 31;    // 32 groups of 4 pixels
    const int cg = t >> 5;    // 8 channel-groups of 32 channels
    const int hwp = hw0 + pg * 4;
    const float* r0 = dict + (size_t)idx_s[pg * 4 + 0] * CCH;
    const float* r1 = dict + (size_t)idx_s[pg * 4 + 1] * CCH;
    const float* r2 = dict + (size_t)idx_s[pg * 4 + 2] * CCH;
    const float* r3 = dict + (size_t)idx_s[pg * 4 + 3] * CCH;
    float* oe = out_base;
    float* op = out_base + EMB_ELEMS;
    const size_t obase = (size_t)n * CCH * HW + hwp;

#pragma unroll
    for (int cq = 0; cq < 8; ++cq) {
        int c = cg * 32 + cq * 4;
        float4 q0 = *(const float4*)(r0 + c);
        float4 q1 = *(const float4*)(r1 + c);
        float4 q2 = *(const float4*)(r2 + c);
        float4 q3 = *(const float4*)(r3 + c);
        float4 v0 = make_float4(q0.x, q1.x, q2.x, q3.x);
        float4 v1 = make_float4(q0.y, q1.y, q2.y, q3.y);
        float4 v2 = make_float4(q0.z, q1.z, q2.z, q3.z);
        float4 v3 = make_float4(q0.w, q1.w, q2.w, q3.w);
        *(float4*)(oe + obase + (size_t)(c + 0) * HW) = v0;
        *(float4*)(op + obase + (size_t)(c + 0) * HW) = v0;
        *(float4*)(oe + obase + (size_t)(c + 1) * HW) = v1;
        *(float4*)(op + obase + (size_t)(c + 1) * HW) = v1;
        *(float4*)(oe + obase + (size_t)(c + 2) * HW) = v2;
        *(float4*)(op + obase + (size_t)(c + 2) * HW) = v2;
        *(float4*)(oe + obase + (size_t)(c + 3) * HW) = v3;
        *(float4*)(op + obase + (size_t)(c + 3) * HW) = v3;
    }
}

// ---------------- Stage 3: exact-fp32 rescue of near-tie pixels --------------
// UNCHANGED (bit-identical arithmetic; coalesced dictT reads).
__global__ __launch_bounds__(256)
void vq_rescue_kernel(const float* __restrict__ x0,
                      const float* __restrict__ x1,
                      const float* __restrict__ dictT,
                      const float* __restrict__ dict,
                      const float* __restrict__ norms,
                      const int* __restrict__ cnts,
                      const int* __restrict__ lists,
                      float* __restrict__ out) {
    __shared__ float xr[CCH];
    __shared__ float rd_s[4];
    __shared__ int   ri_s[4];
    __shared__ int   bi_s;
    const int z = blockIdx.z;
    const float* x = z ? x1 : x0;
    const int* list = lists + (size_t)z * NPIX;
    float* out_emb    = out + (size_t)z * SEC_ELEMS;
    float* out_emb_pt = out_emb + EMB_ELEMS;
    float* out_idx    = out_emb + 2 * EMB_ELEMS;
    const int t    = threadIdx.x;
    const int lane = t & 63;
    const int wv   = t >> 6;
    const int total = cnts[z];

    for (int w = blockIdx.x; w < total; w += gridDim.x) {
        const int g  = list[w];
        const int n  = g / HW;
        const int hw = g % HW;
        xr[t] = x[(size_t)n * CCH * HW + (size_t)t * HW + hw];
        __syncthreads();

        float bd = 3.0e38f; int bi = 0;
#pragma unroll
        for (int dd = 0; dd < 4; ++dd) {          // dicts {t, 256+t, 512+t, 768+t}
            int d = dd * 256 + t;                 // ascending within thread
            float dot = 0.f;
#pragma unroll 8
            for (int k = 0; k < CCH; ++k)
                dot = fmaf(xr[k], dictT[(size_t)k * DDICT + d], dot);
            float dist = fmaf(-2.f, dot, norms[d]);
            if (dist < bd) { bd = dist; bi = d; }
        }
#pragma unroll
        for (int off = 1; off < 64; off <<= 1) {  // wave lexicographic min
            float od = __shfl_xor(bd, off);
            int   oi = __shfl_xor(bi, off);
            if (od < bd || (od == bd && oi < bi)) { bd = od; bi = oi; }
        }
        if (lane == 0) { rd_s[wv] = bd; ri_s[wv] = bi; }
        __syncthreads();
        if (t == 0) {
            float fb = rd_s[0]; int fi = ri_s[0];
#pragma unroll
            for (int q2 = 1; q2 < 4; ++q2)
                if (rd_s[q2] < fb || (rd_s[q2] == fb && ri_s[q2] < fi)) {
                    fb = rd_s[q2]; fi = ri_s[q2];
                }
            bi_s = fi;
            out_idx[g] = (float)fi;
        }
        __syncthreads();
        float v = dict[(size_t)bi_s * CCH + t];
        size_t o = (size_t)n * CCH * HW + (size_t)t * HW + hw;
        out_emb[o]    = v;
        out_emb_pt[o] = v;
        __syncthreads();   // xr reused next iteration
    }
}

extern "C" void kernel_launch(void* const* d_in, const int* in_sizes, int n_in,
                              void* d_out, int out_size, void* d_ws, size_t ws_size,
                              hipStream_t stream) {
    const float* x0   = (const float*)d_in[0];
    const float* x1   = (const float*)d_in[1];
    const float* dict = (const float*)d_in[2];
    float* out = (float*)d_out;

    // ws layout: norms 4K | dHs 512K | dMs 512K | dictT 1M | lists 2x128K | cnts 8
    float*  norms = (float*)d_ws;
    ushort* dHs   = (ushort*)(norms + DDICT);
    ushort* dMs   = dHs + (size_t)DDICT * CCH;
    float*  dictT = (float*)(dMs + (size_t)DDICT * CCH);
    int*    lists = (int*)(dictT + (size_t)DDICT * CCH);   // [2][NPIX]
    int*    cnts  = lists + 2 * NPIX;

    dict_norms_kernel<<<dim3(DDICT / 256), dim3(256), 0, stream>>>(dict, norms, cnts);
    dict_split_kernel<<<dim3(DDICT), dim3(64), 0, stream>>>(dict, dHs, dMs, dictT);

    vq_mfma_kernel<<<dim3(NPIX / TPX, 2), dim3(256), 0, stream>>>(
        x0, x1, dHs, dMs, norms, dict, out, cnts, lists);

    vq_rescue_kernel<<<dim3(1024, 1, 2), dim3(256), 0, stream>>>(
        x0, x1, dictT, dict, norms, cnts, lists, out);
}